// Round 4
// baseline (808.894 us; speedup 1.0000x reference)
//
#include <hip/hip_runtime.h>
#include <math.h>

// Problem constants
#define Bq 2
#define Sq 2048
#define Cq 768
#define Hq 12
#define Dq 64
#define KZ 2              // K-split factor in attention

typedef __bf16 bfv8 __attribute__((ext_vector_type(8)));
typedef float f32x4 __attribute__((ext_vector_type(4)));
#define MFMA16(a, b, c) __builtin_amdgcn_mfma_f32_16x16x32_bf16(a, b, c, 0, 0, 0)

static __device__ inline unsigned short bfbits(float x) {
    __bf16 b = (__bf16)x;
    return __builtin_bit_cast(unsigned short, b);
}
static __device__ inline float bf2f(unsigned short b) {
    return (float)__builtin_bit_cast(__bf16, b);
}
static __device__ inline unsigned short lobits(float x, unsigned short hb) {
    return bfbits(x - bf2f(hb));
}

// ---------------------------------------------------------------------------
// Kernel 0: RoPE cos/sin tables  [S][32] each, fp64-accurate
// ---------------------------------------------------------------------------
__global__ void freq_kernel(float* __restrict__ ctab, float* __restrict__ stab) {
    int idx = blockIdx.x * blockDim.x + threadIdx.x;   // 0..65535
    int s = idx >> 5;
    int i = idx & 31;
    double f = (double)s * exp(-(double)i * 0.28782313662425573); // ln(1e4)/32
    ctab[idx] = (float)cos(f);
    stab[idx] = (float)sin(f);
}

// ---------------------------------------------------------------------------
// Tiled fp32 NT GEMM: out[m][n] = sum_k A[m][k] * B[n][k],  K = 768
// 128x128 tile, BK=16, 256 threads, 8x8 micro-tile per thread.
// MODE 0: QKV + fused RoPE -> writes bf16 hi/lo splits q,k,v in [B,H,S,D]
// MODE 1: proj + bias -> fp32 [M][768] (= final output)
// ---------------------------------------------------------------------------
template <int MODE>
__global__ __launch_bounds__(256) void gemm_kernel(
    const float* __restrict__ A, const float* __restrict__ Bm,
    const float* __restrict__ ctab, const float* __restrict__ stab,
    unsigned short* __restrict__ qhb, unsigned short* __restrict__ qlb,
    unsigned short* __restrict__ khb, unsigned short* __restrict__ klb,
    unsigned short* __restrict__ vhb, unsigned short* __restrict__ vlb,
    float* __restrict__ out0, const float* __restrict__ bias)
{
    __shared__ float aT[16][132];   // aT[k][m]
    __shared__ float bT[16][132];   // bT[k][n]

    const int t  = threadIdx.x;
    const int tx = t & 15;          // 0..15 -> n
    const int ty = t >> 4;          // 0..15 -> m
    const int lrow = t >> 1;        // 0..127 (row of tile being loaded)
    const int kq   = (t & 1) * 8;   // 0 or 8

    const int mBase = blockIdx.y * 128;
    const int nBase = blockIdx.x * 128;

    const float* Ap = A  + (mBase + lrow) * Cq + kq;
    const float* Bp = Bm + (nBase + lrow) * Cq + kq;

    float acc[8][8] = {};

    for (int k0 = 0; k0 < Cq; k0 += 16) {
        float4 a0 = *(const float4*)(Ap + k0);
        float4 a1 = *(const float4*)(Ap + k0 + 4);
        float4 b0 = *(const float4*)(Bp + k0);
        float4 b1 = *(const float4*)(Bp + k0 + 4);
        __syncthreads();   // previous compute finished reading LDS
        aT[kq + 0][lrow] = a0.x; aT[kq + 1][lrow] = a0.y;
        aT[kq + 2][lrow] = a0.z; aT[kq + 3][lrow] = a0.w;
        aT[kq + 4][lrow] = a1.x; aT[kq + 5][lrow] = a1.y;
        aT[kq + 6][lrow] = a1.z; aT[kq + 7][lrow] = a1.w;
        bT[kq + 0][lrow] = b0.x; bT[kq + 1][lrow] = b0.y;
        bT[kq + 2][lrow] = b0.z; bT[kq + 3][lrow] = b0.w;
        bT[kq + 4][lrow] = b1.x; bT[kq + 5][lrow] = b1.y;
        bT[kq + 6][lrow] = b1.z; bT[kq + 7][lrow] = b1.w;
        __syncthreads();
        #pragma unroll
        for (int kk = 0; kk < 16; ++kk) {
            float ar[8], br[8];
            *(float4*)&ar[0] = *(const float4*)&aT[kk][ty * 4];
            *(float4*)&ar[4] = *(const float4*)&aT[kk][64 + ty * 4];
            *(float4*)&br[0] = *(const float4*)&bT[kk][tx * 4];
            *(float4*)&br[4] = *(const float4*)&bT[kk][64 + tx * 4];
            #pragma unroll
            for (int i = 0; i < 8; ++i)
                #pragma unroll
                for (int j = 0; j < 8; ++j)
                    acc[i][j] = fmaf(ar[i], br[j], acc[i][j]);
        }
    }

    if (MODE == 0) {
        const int which = nBase / Cq;   // 0=q 1=k 2=v (128 | 768 -> uniform)
        unsigned short* hp = (which == 0) ? qhb : (which == 1) ? khb : vhb;
        unsigned short* lp = (which == 0) ? qlb : (which == 1) ? klb : vlb;
        #pragma unroll
        for (int ig = 0; ig < 2; ++ig) {
            #pragma unroll
            for (int jg = 0; jg < 2; ++jg) {
                const int cbase = nBase + jg * 64 + tx * 4;
                const int rem   = cbase - which * Cq;
                const int h     = rem >> 6;
                const int dd    = rem & 63;           // aligned to 4
                #pragma unroll
                for (int i = 0; i < 4; ++i) {
                    const int rg = mBase + ig * 64 + ty * 4 + i;
                    const int bb = rg >> 11;
                    const int ss = rg & 2047;
                    float v0 = acc[ig * 4 + i][jg * 4 + 0];
                    float v1 = acc[ig * 4 + i][jg * 4 + 1];
                    float v2 = acc[ig * 4 + i][jg * 4 + 2];
                    float v3 = acc[ig * 4 + i][jg * 4 + 3];
                    float o0, o1, o2, o3;
                    if (which < 2) {
                        const int fi = ss * 32 + (dd >> 1);
                        float c0 = ctab[fi],     s0 = stab[fi];
                        float c1 = ctab[fi + 1], s1 = stab[fi + 1];
                        o0 = v0 * c0 - v1 * s0;  o1 = v1 * c0 + v0 * s0;
                        o2 = v2 * c1 - v3 * s1;  o3 = v3 * c1 + v2 * s1;
                    } else {
                        o0 = v0; o1 = v1; o2 = v2; o3 = v3;
                    }
                    unsigned short h0 = bfbits(o0), h1 = bfbits(o1),
                                   h2 = bfbits(o2), h3 = bfbits(o3);
                    unsigned short l0 = lobits(o0, h0), l1 = lobits(o1, h1),
                                   l2 = lobits(o2, h2), l3 = lobits(o3, h3);
                    const size_t oidx = ((size_t)(bb * Hq + h) * Sq + ss) * Dq + dd;
                    *(ushort4*)&hp[oidx] = make_ushort4(h0, h1, h2, h3);
                    *(ushort4*)&lp[oidx] = make_ushort4(l0, l1, l2, l3);
                }
            }
        }
    } else {
        #pragma unroll
        for (int ig = 0; ig < 2; ++ig) {
            #pragma unroll
            for (int jg = 0; jg < 2; ++jg) {
                const int cbase = nBase + jg * 64 + tx * 4;
                float4 bz = *(const float4*)&bias[cbase];
                #pragma unroll
                for (int i = 0; i < 4; ++i) {
                    const int rg = mBase + ig * 64 + ty * 4 + i;
                    float4 r = make_float4(acc[ig*4+i][jg*4+0] + bz.x,
                                           acc[ig*4+i][jg*4+1] + bz.y,
                                           acc[ig*4+i][jg*4+2] + bz.z,
                                           acc[ig*4+i][jg*4+3] + bz.w);
                    *(float4*)&out0[(size_t)rg * Cq + cbase] = r;
                }
            }
        }
    }
}

// ---------------------------------------------------------------------------
// Kernel 1b: V transpose [B,H,S,D] -> [B,H,D,S], hi+lo packed through LDS.
// Block = 256 threads, one 64(s) x 64(d) tile. Pad 68 -> conflict-free.
// ---------------------------------------------------------------------------
__global__ __launch_bounds__(256) void vtrans_kernel(
    const unsigned short* __restrict__ vhb, const unsigned short* __restrict__ vlb,
    unsigned short* __restrict__ vThb, unsigned short* __restrict__ vTlb)
{
    __shared__ unsigned int lds[64][68];   // lds[d][s], (lo<<16)|hi
    const int t  = threadIdx.x;
    const int st = blockIdx.x;             // s tile (0..31)
    const int bh = blockIdx.y;             // 0..23
    const int lr = t >> 2;                 // 0..63
    const int lc = (t & 3) * 16;

    const size_t ibase = ((size_t)bh * Sq + st * 64) * Dq;
    #pragma unroll
    for (int u = 0; u < 16; u += 8) {
        unsigned short hv[8], lv[8];
        *(uint4*)hv = *(const uint4*)(vhb + ibase + (size_t)lr * Dq + lc + u);
        *(uint4*)lv = *(const uint4*)(vlb + ibase + (size_t)lr * Dq + lc + u);
        #pragma unroll
        for (int j = 0; j < 8; ++j)
            lds[lc + u + j][lr] = (unsigned)hv[j] | ((unsigned)lv[j] << 16);
    }
    __syncthreads();
    const int d  = t >> 2;
    const int sc = (t & 3) * 16;
    const size_t obase = ((size_t)bh * Dq + d) * Sq + st * 64 + sc;
    #pragma unroll
    for (int u = 0; u < 16; u += 8) {
        unsigned arr[8];
        *(uint4*)&arr[0] = *(const uint4*)&lds[d][sc + u];
        *(uint4*)&arr[4] = *(const uint4*)&lds[d][sc + u + 4];
        unsigned short h[8], l[8];
        #pragma unroll
        for (int j = 0; j < 8; ++j) {
            h[j] = (unsigned short)(arr[j] & 0xffffu);
            l[j] = (unsigned short)(arr[j] >> 16);
        }
        *(uint4*)(vThb + obase + u) = *(const uint4*)h;
        *(uint4*)(vTlb + obase + u) = *(const uint4*)l;
    }
}

// ---------------------------------------------------------------------------
// Kernel 2: MFMA flash attention, bf16 3-term split, K-split by KZ.
// Block = 4 waves; wave w owns q-rows [qt*64 + w*16, +16); kz = blockIdx.z
// processes K tiles [kz*32/KZ, (kz+1)*32/KZ). Emits unnormalized partial O
// (fp32) + per-row (m, l) for the combine kernel.
// ---------------------------------------------------------------------------
__global__ __launch_bounds__(256, 6) void attn_mfma_kernel(
    const unsigned short* __restrict__ qhb, const unsigned short* __restrict__ qlb,
    const unsigned short* __restrict__ khb, const unsigned short* __restrict__ klb,
    const unsigned short* __restrict__ vThb, const unsigned short* __restrict__ vTlb,
    float* __restrict__ Opart, float2* __restrict__ mlp)
{
    __shared__ unsigned int pbuf[4][16][68];   // per-wave P tile, (lo<<16)|hi

    const int t    = threadIdx.x;
    const int w    = t >> 6;
    const int lane = t & 63;
    const int ml   = lane & 15;
    const int quad = lane >> 4;
    const int qt = blockIdx.x;      // 0..31
    const int bh = blockIdx.y;      // 0..23
    const int kz = blockIdx.z;      // 0..KZ-1

    // ---- Q fragments (A-layout): row m=ml, k = ks*32 + quad*8 + j ----
    const size_t qoff = ((size_t)bh * Sq + qt * 64 + w * 16 + ml) * Dq + quad * 8;
    bfv8 aQh[2], aQl[2];
    #pragma unroll
    for (int ks = 0; ks < 2; ++ks) {
        aQh[ks] = *(const bfv8*)(qhb + qoff + ks * 32);
        aQl[ks] = *(const bfv8*)(qlb + qoff + ks * 32);
    }

    float m_st[4], l_st[4];
    f32x4 O[4];
    #pragma unroll
    for (int r = 0; r < 4; ++r) { m_st[r] = -INFINITY; l_st[r] = 0.f; }
    #pragma unroll
    for (int ng = 0; ng < 4; ++ng) O[ng] = (f32x4){0.f, 0.f, 0.f, 0.f};

    const int ktBeg = kz * (32 / KZ);
    const int ktEnd = ktBeg + (32 / KZ);
    for (int kt = ktBeg; kt < ktEnd; ++kt) {
        // ---- scores S = Q K^T : B-frag n = key, k = d ----
        f32x4 S[4];
        const size_t kbase = ((size_t)bh * Sq + kt * 64) * Dq + quad * 8;
        #pragma unroll
        for (int ng = 0; ng < 4; ++ng) {
            f32x4 acc = (f32x4){0.f, 0.f, 0.f, 0.f};
            #pragma unroll
            for (int ks = 0; ks < 2; ++ks) {
                const size_t ko = kbase + (size_t)(ng * 16 + ml) * Dq + ks * 32;
                bfv8 bKh = *(const bfv8*)(khb + ko);
                bfv8 bKl = *(const bfv8*)(klb + ko);
                acc = MFMA16(aQh[ks], bKh, acc);
                acc = MFMA16(aQl[ks], bKh, acc);
                acc = MFMA16(aQh[ks], bKl, acc);
            }
            S[ng] = acc;
        }

        // ---- online softmax (rows = quad*4 + r, cols across 16 lanes) ----
        float nm[4], alpha[4];
        #pragma unroll
        for (int r = 0; r < 4; ++r) {
            float mx = fmaxf(fmaxf(S[0][r], S[1][r]), fmaxf(S[2][r], S[3][r])) * 0.125f;
            #pragma unroll
            for (int off = 1; off < 16; off <<= 1)
                mx = fmaxf(mx, __shfl_xor(mx, off, 64));
            nm[r] = fmaxf(m_st[r], mx);
            alpha[r] = __expf(m_st[r] - nm[r]);
            m_st[r] = nm[r];
        }
        float ps[4] = {0.f, 0.f, 0.f, 0.f};
        #pragma unroll
        for (int ng = 0; ng < 4; ++ng) {
            #pragma unroll
            for (int r = 0; r < 4; ++r) {
                float p = __expf(S[ng][r] * 0.125f - nm[r]);
                ps[r] += p;
                unsigned short ph = bfbits(p);
                unsigned short pl = lobits(p, ph);
                pbuf[w][quad * 4 + r][ng * 16 + ml] =
                    (unsigned int)ph | ((unsigned int)pl << 16);
            }
        }
        #pragma unroll
        for (int r = 0; r < 4; ++r) {
            #pragma unroll
            for (int off = 1; off < 16; off <<= 1)
                ps[r] += __shfl_xor(ps[r], off, 64);
            l_st[r] = l_st[r] * alpha[r] + ps[r];
            O[0][r] *= alpha[r]; O[1][r] *= alpha[r];
            O[2][r] *= alpha[r]; O[3][r] *= alpha[r];
        }

        // ---- read P back as A-frags (wave-private LDS, DS pipe in-order) ----
        bfv8 aPh[2], aPl[2];
        #pragma unroll
        for (int ks = 0; ks < 2; ++ks) {
            const unsigned int* src = &pbuf[w][ml][ks * 32 + quad * 8];
            uint4 w0 = *(const uint4*)src;
            uint4 w1 = *(const uint4*)(src + 4);
            union { unsigned short s[8]; bfv8 v; } hu, lu;
            unsigned int arr[8] = {w0.x, w0.y, w0.z, w0.w, w1.x, w1.y, w1.z, w1.w};
            #pragma unroll
            for (int j = 0; j < 8; ++j) {
                hu.s[j] = (unsigned short)(arr[j] & 0xffffu);
                lu.s[j] = (unsigned short)(arr[j] >> 16);
            }
            aPh[ks] = hu.v;
            aPl[ks] = lu.v;
        }

        // ---- O += P V : B-frag n = d (vT[d][key]), k = key ----
        const size_t vbase = (size_t)bh * Dq * Sq + kt * 64 + quad * 8;
        #pragma unroll
        for (int ng = 0; ng < 4; ++ng) {
            #pragma unroll
            for (int ks = 0; ks < 2; ++ks) {
                const size_t vo = vbase + (size_t)(ng * 16 + ml) * Sq + ks * 32;
                bfv8 bVh = *(const bfv8*)(vThb + vo);
                bfv8 bVl = *(const bfv8*)(vTlb + vo);
                O[ng] = MFMA16(aPh[ks], bVh, O[ng]);
                O[ng] = MFMA16(aPl[ks], bVh, O[ng]);
                O[ng] = MFMA16(aPh[ks], bVl, O[ng]);
            }
        }
    }

    // ---- epilogue: write unnormalized partial O + (m,l) ----
    const size_t PART = (size_t)Bq * Hq * Sq * Dq;
    float* Op = Opart + PART * kz;
    #pragma unroll
    for (int r = 0; r < 4; ++r) {
        const int srow = qt * 64 + w * 16 + quad * 4 + r;
        const size_t row = (size_t)bh * Sq + srow;
        #pragma unroll
        for (int ng = 0; ng < 4; ++ng)
            Op[row * Dq + ng * 16 + ml] = O[ng][r];
        if (ml == 0)
            mlp[(size_t)kz * Bq * Hq * Sq + row] = make_float2(m_st[r], l_st[r]);
    }
}

// ---------------------------------------------------------------------------
// Kernel 3: combine KZ partial (O, m, l) -> attn [B,S,C] fp32
// ---------------------------------------------------------------------------
__global__ __launch_bounds__(256) void combine_kernel(
    const float* __restrict__ Opart, const float2* __restrict__ mlp,
    float* __restrict__ attn)
{
    const int idx = blockIdx.x * blockDim.x + threadIdx.x;  // BHSD/4 threads
    const int d4 = idx & 15;
    const int s  = (idx >> 4) & (Sq - 1);
    const int bh = idx >> 15;
    const size_t row  = (size_t)bh * Sq + s;
    const size_t PART = (size_t)Bq * Hq * Sq * Dq;
    const size_t MLP  = (size_t)Bq * Hq * Sq;

    float2 ml0 = mlp[row];
    float m = ml0.x;
    #pragma unroll
    for (int z = 1; z < KZ; ++z) m = fmaxf(m, mlp[z * MLP + row].x);

    float4 acc = make_float4(0.f, 0.f, 0.f, 0.f);
    float l = 0.f;
    #pragma unroll
    for (int z = 0; z < KZ; ++z) {
        float2 mlz = mlp[z * MLP + row];
        float wz = __expf(mlz.x - m);
        float4 Oz = *(const float4*)(Opart + z * PART + row * Dq + d4 * 4);
        acc.x += Oz.x * wz; acc.y += Oz.y * wz;
        acc.z += Oz.z * wz; acc.w += Oz.w * wz;
        l += mlz.y * wz;
    }
    const float il = 1.0f / l;
    const int bb = bh / Hq, hh = bh % Hq;
    float4 r = make_float4(acc.x * il, acc.y * il, acc.z * il, acc.w * il);
    *(float4*)&attn[((size_t)(bb * Sq + s)) * Cq + hh * Dq + d4 * 4] = r;
}

// ---------------------------------------------------------------------------
extern "C" void kernel_launch(void* const* d_in, const int* in_sizes, int n_in,
                              void* d_out, int out_size, void* d_ws, size_t ws_size,
                              hipStream_t stream) {
    const float* x     = (const float*)d_in[0];
    const float* Wqkv  = (const float*)d_in[1];
    const float* Wproj = (const float*)d_in[2];
    const float* bproj = (const float*)d_in[3];
    float* out = (float*)d_out;

    const size_t BHSD = (size_t)Bq * Hq * Sq * Dq;   // 3,145,728
    char* p = (char*)d_ws;
    unsigned short* qhb  = (unsigned short*)p; p += BHSD * 2;
    unsigned short* qlb  = (unsigned short*)p; p += BHSD * 2;
    unsigned short* khb  = (unsigned short*)p; p += BHSD * 2;
    unsigned short* klb  = (unsigned short*)p; p += BHSD * 2;
    unsigned short* vhb  = (unsigned short*)p; p += BHSD * 2;
    unsigned short* vlb  = (unsigned short*)p; p += BHSD * 2;
    unsigned short* vThb = (unsigned short*)p; p += BHSD * 2;
    unsigned short* vTlb = (unsigned short*)p; p += BHSD * 2;
    float*  attn  = (float*)p;  p += BHSD * 4;
    float*  Opart = (float*)p;  p += (size_t)KZ * BHSD * 4;
    float2* mlp   = (float2*)p; p += (size_t)KZ * Bq * Hq * Sq * 8;
    float*  ctab  = (float*)p;  p += (size_t)Sq * 32 * 4;
    float*  stab  = (float*)p;  p += (size_t)Sq * 32 * 4;
    // total ws use ~90 MB

    freq_kernel<<<256, 256, 0, stream>>>(ctab, stab);
    gemm_kernel<0><<<dim3(18, 32), 256, 0, stream>>>(
        x, Wqkv, ctab, stab, qhb, qlb, khb, klb, vhb, vlb, nullptr, nullptr);
    vtrans_kernel<<<dim3(32, 24), 256, 0, stream>>>(vhb, vlb, vThb, vTlb);
    attn_mfma_kernel<<<dim3(32, 24, KZ), 256, 0, stream>>>(
        qhb, qlb, khb, klb, vThb, vTlb, Opart, mlp);
    combine_kernel<<<(int)(BHSD / 4 / 256), 256, 0, stream>>>(Opart, mlp, attn);
    gemm_kernel<1><<<dim3(6, 32), 256, 0, stream>>>(
        attn, Wproj, ctab, stab, nullptr, nullptr, nullptr, nullptr, nullptr, nullptr,
        out, bproj);
}